// Round 17
// baseline (65.757 us; speedup 1.0000x reference)
//
#include <hip/hip_runtime.h>
#include <hip/hip_bf16.h>

typedef __bf16 bf16x8 __attribute__((ext_vector_type(8)));
typedef float  f32x4  __attribute__((ext_vector_type(4)));

static constexpr int NB = 8;
static constexpr int S  = 2048;
static constexpr int T  = 2048;
static constexpr int D  = 128;

// Single fused kernel. Grid 1024 (round-robin => b = blk&7 is XCD-local batch),
// 512 threads, 64 KB LDS -> 2 blocks/CU. Each block normalizes its own panels
// in-kernel (no ws, no prep kernel, no launch gap):
//   prologue: S panel -> bf16 image in ldsX; T0 panel -> image in ldsT;
//             bregs (src operand) read from ldsX into registers.
//   tile0:    K-loop; issue raw T1 loads; epilogue0 (ldsX transpose, vmcnt(8)
//             retires T1 loads under 8 in-flight stores); normalize T1 -> ldsT.
//   tile1:    K-loop; epilogue1.
// bf16 image layout (rows 0..127, 16 uint4/row): logical slot q at q^(row&7).
__global__ __launch_bounds__(512, 4)
void fused(const float* __restrict__ src, const float* __restrict__ tar,
           const int* __restrict__ ms, const int* __restrict__ mt,
           float* __restrict__ out)
{
    __shared__ uint4 ldsT[128 * 16];   // 32 KB  T-panel bf16 image
    __shared__ uint4 ldsX[128 * 16];   // 32 KB  S-image (prologue) / f32 epilogue buf [64][32]

    const int blk = blockIdx.x;        // 0..1023
    const int b   = blk & 7;           // batch == XCD (round-robin)
    const int j   = blk >> 3;          // 0..127
    const int ts  = j >> 3;            // 0..15  source tile (128 rows)
    const int tp  = j & 7;             // 0..7   target pair (2 x 128 rows)

    const int tid  = threadIdx.x;
    const int row4 = tid >> 2;         // 0..127  (staging: 4 threads per row)
    const int q    = tid & 3;          // quarter-row (32 floats)

    const int lane = tid & 63;
    const int w    = tid >> 6;
    const int wt   = w & 1;            // 0..1  t-half (64 t-rows)
    const int wsp  = w >> 1;           // 0..3  s-quarter (32 s-rows)
    const int r16  = lane & 15;
    const int kg   = lane >> 4;        // 0..3
    const int swz  = r16 & 7;

    // per-staged-row masks (unconditional vector loads -> wave-uniform vmcnt)
    const int mS  = ms[b * S + ts * 128 + row4];
    const int mT0 = mt[b * T + tp * 256 + row4];
    const int mT1 = mt[b * T + tp * 256 + 128 + row4];

    // ---- stage S panel -> ldsX bf16 image ----
    {
        const float* p = src + ((size_t)(b * S + ts * 128 + row4)) * D + q * 32;
        f32x4 v[8]; float ss = 0.f;
        #pragma unroll
        for (int i = 0; i < 8; ++i) {
            v[i] = ((const f32x4*)p)[i];
            ss += v[i][0]*v[i][0] + v[i][1]*v[i][1] + v[i][2]*v[i][2] + v[i][3]*v[i][3];
        }
        ss += __shfl_xor(ss, 1); ss += __shfl_xor(ss, 2);
        const float sc = mS ? (1.0f / fmaxf(sqrtf(ss), 1e-12f)) : 0.0f;
        #pragma unroll
        for (int i = 0; i < 4; ++i) {
            const f32x4 u0 = v[2*i], u1 = v[2*i+1];
            bf16x8 t;
            t[0]=(__bf16)(u0[0]*sc); t[1]=(__bf16)(u0[1]*sc);
            t[2]=(__bf16)(u0[2]*sc); t[3]=(__bf16)(u0[3]*sc);
            t[4]=(__bf16)(u1[0]*sc); t[5]=(__bf16)(u1[1]*sc);
            t[6]=(__bf16)(u1[2]*sc); t[7]=(__bf16)(u1[3]*sc);
            ldsX[row4 * 16 + ((q*4+i) ^ (row4 & 7))] = __builtin_bit_cast(uint4, t);
        }
    }
    // ---- stage T0 panel -> ldsT bf16 image ----
    {
        const float* p = tar + ((size_t)(b * T + tp * 256 + row4)) * D + q * 32;
        f32x4 v[8]; float ss = 0.f;
        #pragma unroll
        for (int i = 0; i < 8; ++i) {
            v[i] = ((const f32x4*)p)[i];
            ss += v[i][0]*v[i][0] + v[i][1]*v[i][1] + v[i][2]*v[i][2] + v[i][3]*v[i][3];
        }
        ss += __shfl_xor(ss, 1); ss += __shfl_xor(ss, 2);
        const float sc = mT0 ? (1.0f / fmaxf(sqrtf(ss), 1e-12f)) : 0.0f;
        #pragma unroll
        for (int i = 0; i < 4; ++i) {
            const f32x4 u0 = v[2*i], u1 = v[2*i+1];
            bf16x8 t;
            t[0]=(__bf16)(u0[0]*sc); t[1]=(__bf16)(u0[1]*sc);
            t[2]=(__bf16)(u0[2]*sc); t[3]=(__bf16)(u0[3]*sc);
            t[4]=(__bf16)(u1[0]*sc); t[5]=(__bf16)(u1[1]*sc);
            t[6]=(__bf16)(u1[2]*sc); t[7]=(__bf16)(u1[3]*sc);
            ldsT[row4 * 16 + ((q*4+i) ^ (row4 & 7))] = __builtin_bit_cast(uint4, t);
        }
    }
    __syncthreads();

    // ---- B operand (src rows) from ldsX image into registers ----
    bf16x8 bregs[2][4];
    #pragma unroll
    for (int n = 0; n < 2; ++n)
        #pragma unroll
        for (int ks = 0; ks < 4; ++ks) {
            const int R = wsp * 32 + n * 16 + r16;          // local s-row
            bregs[n][ks] = __builtin_bit_cast(bf16x8, ldsX[R * 16 + ((ks*4+kg) ^ swz)]);
        }
    __syncthreads();   // all bregs read before epilogue reuses ldsX

    f32x4 acc[4][2];
    f32x4 tv[8];       // T1 raw staging registers

    #pragma unroll
    for (int tile = 0; tile < 2; ++tile) {
        #pragma unroll
        for (int m = 0; m < 4; ++m)
            #pragma unroll
            for (int n = 0; n < 2; ++n)
                acc[m][n] = f32x4{0.f, 0.f, 0.f, 0.f};

        #pragma unroll
        for (int ks = 0; ks < 4; ++ks) {          // K = 4 * 32
            bf16x8 at[4];
            #pragma unroll
            for (int m = 0; m < 4; ++m) {
                const int rl = wt * 64 + m * 16 + r16;
                at[m] = __builtin_bit_cast(bf16x8, ldsT[rl * 16 + ((ks*4+kg) ^ swz)]);
            }
            #pragma unroll
            for (int m = 0; m < 4; ++m)
                #pragma unroll
                for (int n = 0; n < 2; ++n)
                    acc[m][n] = __builtin_amdgcn_mfma_f32_16x16x32_bf16(at[m], bregs[n][ks], acc[m][n], 0, 0, 0);
        }

        if (tile == 0) {
            // issue raw T1 loads now; they retire under epilogue0's stores
            const float* p1 = tar + ((size_t)(b * T + tp * 256 + 128 + row4)) * D + q * 32;
            #pragma unroll
            for (int i = 0; i < 8; ++i) tv[i] = ((const f32x4*)p1)[i];
            __builtin_amdgcn_sched_barrier(0);     // pin: loads issued before stores
        }

        // ---- epilogue: acc -> ldsX (64-row halves) -> 2rows x 512B wave stores ----
        const int ttc = tp * 2 + tile;
        #pragma unroll
        for (int h = 0; h < 2; ++h) {
            if ((wsp >> 1) == h) {                 // waves owning s-rows [h*64, h*64+64)
                #pragma unroll
                for (int m = 0; m < 4; ++m)
                    #pragma unroll
                    for (int n = 0; n < 2; ++n) {
                        const int lrow = (wsp & 1) * 32 + n * 16 + r16;   // 0..63
                        const int col  = wt * 16 + m * 4 + kg;            // 0..31
                        const f32x4 a = acc[m][n];
                        f32x4 o;
                        o[0] = fmaxf(a[0], 0.f);
                        o[1] = fmaxf(a[1], 0.f);
                        o[2] = fmaxf(a[2], 0.f);
                        o[3] = fmaxf(a[3], 0.f);
                        ldsX[lrow * 32 + (col ^ (lrow & 31))] = __builtin_bit_cast(uint4, o);
                    }
            }
            asm volatile("s_waitcnt lgkmcnt(0)" ::: "memory");
            __builtin_amdgcn_s_barrier();
            __builtin_amdgcn_sched_barrier(0);

            #pragma unroll
            for (int it = 0; it < 4; ++it) {       // 64 rows x 32 uint4 cooperative store
                const int flat = it * 512 + tid;   // 0..2047
                const int row  = flat >> 5;        // 0..63
                const int col  = flat & 31;
                const uint4 vv = ldsX[row * 32 + (col ^ (row & 31))];
                float* po = out + ((size_t)(b * S + ts * 128 + h * 64 + row)) * T
                                + (size_t)ttc * 128 + col * 4;
                *(f32x4*)po = __builtin_bit_cast(f32x4, vv);
            }

            asm volatile("s_waitcnt lgkmcnt(0)" ::: "memory");   // ldsX reads done
            if (tile == 0 && h == 1)
                asm volatile("s_waitcnt vmcnt(8)" ::: "memory"); // retire 8 T1 loads (8 stores younger)
            __builtin_amdgcn_s_barrier();
            __builtin_amdgcn_sched_barrier(0);
        }

        if (tile == 0) {
            // finish T1 stage: normalize (loads retired by vmcnt(8)) -> ldsT image
            float ss = 0.f;
            #pragma unroll
            for (int i = 0; i < 8; ++i)
                ss += tv[i][0]*tv[i][0] + tv[i][1]*tv[i][1] + tv[i][2]*tv[i][2] + tv[i][3]*tv[i][3];
            ss += __shfl_xor(ss, 1); ss += __shfl_xor(ss, 2);
            const float sc = mT1 ? (1.0f / fmaxf(sqrtf(ss), 1e-12f)) : 0.0f;
            #pragma unroll
            for (int i = 0; i < 4; ++i) {
                const f32x4 u0 = tv[2*i], u1 = tv[2*i+1];
                bf16x8 t;
                t[0]=(__bf16)(u0[0]*sc); t[1]=(__bf16)(u0[1]*sc);
                t[2]=(__bf16)(u0[2]*sc); t[3]=(__bf16)(u0[3]*sc);
                t[4]=(__bf16)(u1[0]*sc); t[5]=(__bf16)(u1[1]*sc);
                t[6]=(__bf16)(u1[2]*sc); t[7]=(__bf16)(u1[3]*sc);
                ldsT[row4 * 16 + ((q*4+i) ^ (row4 & 7))] = __builtin_bit_cast(uint4, t);
            }
            asm volatile("s_waitcnt lgkmcnt(0)" ::: "memory");   // T1 image visible
            __builtin_amdgcn_s_barrier();                         // before tile1 K-loop reads
            __builtin_amdgcn_sched_barrier(0);
        }
    }
}

extern "C" void kernel_launch(void* const* d_in, const int* in_sizes, int n_in,
                              void* d_out, int out_size, void* d_ws, size_t ws_size,
                              hipStream_t stream) {
    const float* src    = (const float*)d_in[0];
    const float* tar    = (const float*)d_in[1];
    const int*   mask_s = (const int*)d_in[2];
    const int*   mask_t = (const int*)d_in[3];
    float*       out    = (float*)d_out;

    hipLaunchKernelGGL(fused, dim3(1024), dim3(512), 0, stream, src, tar, mask_s, mask_t, out);
}

// Round 18
// 34.742 us; speedup vs baseline: 1.8927x; 1.8927x over previous
//
#include <hip/hip_runtime.h>
#include <hip/hip_bf16.h>

typedef __bf16 bf16x8 __attribute__((ext_vector_type(8)));
typedef float  f32x4  __attribute__((ext_vector_type(4)));

static constexpr int NB = 8;
static constexpr int S  = 2048;
static constexpr int T  = 2048;
static constexpr int D  = 128;

// ws layout: wsrc[16384 rows][16 uint4], wtar[16384 rows][16 uint4]  (8 MB)
// Each row: 128 bf16 (normalized, mask-folded), slot q stored at (q ^ (row&7))
// == the exact LDS image the GEMM wants (global_load_lds copies linearly).

__device__ __forceinline__ void g2l(const uint4* g, uint4* l) {
    __builtin_amdgcn_global_load_lds((const __attribute__((address_space(1))) void*)g,
                                     (__attribute__((address_space(3))) void*)l, 16, 0, 0);
}

// ---------------- pass 1: normalize + mask-zero + bf16 + swizzled image ----------------
// XCD-local ownership: block p preps batch (p&7); with round-robin block->XCD
// dispatch, batch b's ws image is written and re-read on XCD b (dirty-local L2).
__global__ __launch_bounds__(512, 2)
void prep(const float* __restrict__ src, const float* __restrict__ tar,
          const int* __restrict__ ms, const int* __restrict__ mt,
          uint4* __restrict__ ws)
{
    const int tid   = threadIdx.x;
    const int p     = blockIdx.x;               // 0..255
    const int b     = p & 7;                    // batch == XCD (round-robin)
    const int chunk = p >> 3;                   // 0..31
    const int lr    = chunk * 128 + (tid >> 2); // 0..4095 batch-local row (src then tar)
    const int q     = tid & 3;                  // quarter-row
    const bool isT  = lr >= 2048;
    const int  r    = b * 2048 + (lr & 2047);   // global row within src/tar
    const float* pp = (isT ? tar : src) + (size_t)r * D + q * 32;
    const int   mk  = (isT ? mt : ms)[r];
    uint4*      wp  = ws + ((size_t)(isT ? NB * S : 0) + r) * 16;

    float4 v[8];
    float ss = 0.f;
    if (mk) {
        #pragma unroll
        for (int j = 0; j < 8; ++j) {
            v[j] = ((const float4*)pp)[j];
            ss += v[j].x * v[j].x + v[j].y * v[j].y + v[j].z * v[j].z + v[j].w * v[j].w;
        }
    } else {
        #pragma unroll
        for (int j = 0; j < 8; ++j) v[j] = float4{0.f, 0.f, 0.f, 0.f};
    }
    ss += __shfl_xor(ss, 1);                    // 4-lane group reduce (lanes of one row)
    ss += __shfl_xor(ss, 2);
    const float sc = mk ? (1.0f / fmaxf(sqrtf(ss), 1e-12f)) : 0.0f;

    #pragma unroll
    for (int i = 0; i < 4; ++i) {
        const float4 u0 = v[2 * i], u1 = v[2 * i + 1];
        bf16x8 t;
        t[0] = (__bf16)(u0.x * sc); t[1] = (__bf16)(u0.y * sc);
        t[2] = (__bf16)(u0.z * sc); t[3] = (__bf16)(u0.w * sc);
        t[4] = (__bf16)(u1.x * sc); t[5] = (__bf16)(u1.y * sc);
        t[6] = (__bf16)(u1.z * sc); t[7] = (__bf16)(u1.w * sc);
        wp[(q * 4 + i) ^ (r & 7)] = __builtin_bit_cast(uint4, t);
    }
}

// ---------------- pass 2: tiled GEMM, double-buffered T panel, direct stores ----------
// 1024 blocks (b=blk&7 -> XCD-local ws reads), 512 thr, 64 KB LDS -> 2 blocks/CU.
// T1 prefetch issues immediately after T0 arrives (hidden under tile0 K-loop +
// stores). Direct f32x4 stores from acc (no LDS transpose): 3 barriers/block.
__global__ __launch_bounds__(512, 4)
void gemm(const uint4* __restrict__ ws, float* __restrict__ out)
{
    __shared__ uint4 ldsT[2][128 * 16];   // 2 x 32 KB  double-buffered tar panel

    const uint4* wsrc = ws;
    const uint4* wtar = ws + (size_t)NB * S * 16;

    const int blk = blockIdx.x;        // 0..1023 ; round-robin => b == XCD id
    const int b   = blk & 7;
    const int j   = blk >> 3;          // 0..127
    const int ts  = j >> 3;            // 0..15  source tile (128 rows)
    const int tp  = j & 7;             // 0..7   target pair (2 x 128 rows)

    const int tid  = threadIdx.x;
    const int lane = tid & 63;
    const int w    = tid >> 6;
    const int wt   = w & 1;            // 0..1  t-half (64 t-rows)
    const int wsp  = w >> 1;           // 0..3  s-quarter (32 s-rows)
    const int r16  = lane & 15;
    const int kg   = lane >> 4;        // 0..3
    const int swz  = r16 & 7;

    // ---- B operand (src rows) directly into registers, once per block ----
    bf16x8 bregs[2][4];
    #pragma unroll
    for (int n = 0; n < 2; ++n)
        #pragma unroll
        for (int ks = 0; ks < 4; ++ks) {
            const int R = b * S + ts * 128 + wsp * 32 + n * 16 + r16;
            bregs[n][ks] = __builtin_bit_cast(bf16x8, wsrc[(size_t)R * 16 + ((ks * 4 + kg) ^ swz)]);
        }

    // ---- stage T0; then immediately issue T1 prefetch (hidden under tile0) ----
    const uint4* gt0 = wtar + ((size_t)(b * T + tp * 256)) * 16;
    const uint4* gt1 = gt0 + 128 * 16;
    #pragma unroll
    for (int i = 0; i < 4; ++i)
        g2l(gt0 + i * 512 + tid, &ldsT[0][i * 512 + w * 64]);
    asm volatile("s_waitcnt vmcnt(0)" ::: "memory");   // T0 resident (bregs also retired)
    __builtin_amdgcn_s_barrier();
    __builtin_amdgcn_sched_barrier(0);
    #pragma unroll
    for (int i = 0; i < 4; ++i)
        g2l(gt1 + i * 512 + tid, &ldsT[1][i * 512 + w * 64]);
    __builtin_amdgcn_sched_barrier(0);                 // T1 loads issued before anything else

    f32x4 acc[4][2];

    #pragma unroll
    for (int tile = 0; tile < 2; ++tile) {
        #pragma unroll
        for (int m = 0; m < 4; ++m)
            #pragma unroll
            for (int n = 0; n < 2; ++n)
                acc[m][n] = f32x4{0.f, 0.f, 0.f, 0.f};

        #pragma unroll
        for (int ks = 0; ks < 4; ++ks) {          // K = 4 * 32
            bf16x8 at[4];
            #pragma unroll
            for (int m = 0; m < 4; ++m) {
                const int rl = wt * 64 + m * 16 + r16;
                at[m] = __builtin_bit_cast(bf16x8, ldsT[tile][rl * 16 + ((ks * 4 + kg) ^ swz)]);
            }
            #pragma unroll
            for (int m = 0; m < 4; ++m)
                #pragma unroll
                for (int n = 0; n < 2; ++n)
                    acc[m][n] = __builtin_amdgcn_mfma_f32_16x16x32_bf16(at[m], bregs[n][ks], acc[m][n], 0, 0, 0);
        }

        // ---- epilogue: ReLU + direct f32x4 stores (norms & masks folded in prep) ----
        const int ttc = tp * 2 + tile;
        #pragma unroll
        for (int m = 0; m < 4; ++m) {
            const int tl = wt * 64 + m * 16 + kg * 4;
            #pragma unroll
            for (int n = 0; n < 2; ++n) {
                const int sl = wsp * 32 + n * 16 + r16;
                const f32x4 a = acc[m][n];
                f32x4 o;
                o[0] = fmaxf(a[0], 0.f);
                o[1] = fmaxf(a[1], 0.f);
                o[2] = fmaxf(a[2], 0.f);
                o[3] = fmaxf(a[3], 0.f);
                float* po = out + ((size_t)(b * S + ts * 128 + sl)) * T + (size_t)ttc * 128 + tl;
                *(f32x4*)po = o;
            }
        }

        if (tile == 0) {
            // T1's 4 loads are the oldest vmem ops; 8 stores may stay in flight
            asm volatile("s_waitcnt vmcnt(8)" ::: "memory");
            __builtin_amdgcn_s_barrier();
            __builtin_amdgcn_sched_barrier(0);
        }
    }
}

extern "C" void kernel_launch(void* const* d_in, const int* in_sizes, int n_in,
                              void* d_out, int out_size, void* d_ws, size_t ws_size,
                              hipStream_t stream) {
    const float* src    = (const float*)d_in[0];
    const float* tar    = (const float*)d_in[1];
    const int*   mask_s = (const int*)d_in[2];
    const int*   mask_t = (const int*)d_in[3];
    float*       out    = (float*)d_out;
    uint4*       ws     = (uint4*)d_ws;

    hipLaunchKernelGGL(prep, dim3(256), dim3(512), 0, stream, src, tar, mask_s, mask_t, ws);
    hipLaunchKernelGGL(gemm, dim3(1024), dim3(512), 0, stream, ws, out);
}

// Round 19
// 33.723 us; speedup vs baseline: 1.9499x; 1.0302x over previous
//
#include <hip/hip_runtime.h>
#include <hip/hip_bf16.h>

typedef __bf16 bf16x8 __attribute__((ext_vector_type(8)));
typedef float  f32x4  __attribute__((ext_vector_type(4)));

static constexpr int NB = 8;
static constexpr int S  = 2048;
static constexpr int T  = 2048;
static constexpr int D  = 128;

// ws layout: wsrc[16384 rows][16 uint4], wtar[16384 rows][16 uint4]  (8 MB)
// Each row: 128 bf16 (normalized, mask-folded), slot q stored at (q ^ (row&7))
// == the exact LDS image the GEMM wants (global_load_lds copies linearly).

__device__ __forceinline__ void g2l(const uint4* g, uint4* l) {
    __builtin_amdgcn_global_load_lds((const __attribute__((address_space(1))) void*)g,
                                     (__attribute__((address_space(3))) void*)l, 16, 0, 0);
}

// ---------------- pass 1: normalize + mask-zero + bf16 + swizzled image ----------------
// XCD-local ownership: block p preps batch (p&7); with round-robin block->XCD
// dispatch, batch b's ws image is written and re-read on XCD b (dirty-local L2).
__global__ __launch_bounds__(512, 2)
void prep(const float* __restrict__ src, const float* __restrict__ tar,
          const int* __restrict__ ms, const int* __restrict__ mt,
          uint4* __restrict__ ws)
{
    const int tid   = threadIdx.x;
    const int p     = blockIdx.x;               // 0..255
    const int b     = p & 7;                    // batch == XCD (round-robin)
    const int chunk = p >> 3;                   // 0..31
    const int lr    = chunk * 128 + (tid >> 2); // 0..4095 batch-local row (src then tar)
    const int q     = tid & 3;                  // quarter-row
    const bool isT  = lr >= 2048;
    const int  r    = b * 2048 + (lr & 2047);   // global row within src/tar
    const float* pp = (isT ? tar : src) + (size_t)r * D + q * 32;
    const int   mk  = (isT ? mt : ms)[r];
    uint4*      wp  = ws + ((size_t)(isT ? NB * S : 0) + r) * 16;

    float4 v[8];
    float ss = 0.f;
    if (mk) {
        #pragma unroll
        for (int j = 0; j < 8; ++j) {
            v[j] = ((const float4*)pp)[j];
            ss += v[j].x * v[j].x + v[j].y * v[j].y + v[j].z * v[j].z + v[j].w * v[j].w;
        }
    } else {
        #pragma unroll
        for (int j = 0; j < 8; ++j) v[j] = float4{0.f, 0.f, 0.f, 0.f};
    }
    ss += __shfl_xor(ss, 1);                    // 4-lane group reduce (lanes of one row)
    ss += __shfl_xor(ss, 2);
    const float sc = mk ? (1.0f / fmaxf(sqrtf(ss), 1e-12f)) : 0.0f;

    #pragma unroll
    for (int i = 0; i < 4; ++i) {
        const float4 u0 = v[2 * i], u1 = v[2 * i + 1];
        bf16x8 t;
        t[0] = (__bf16)(u0.x * sc); t[1] = (__bf16)(u0.y * sc);
        t[2] = (__bf16)(u0.z * sc); t[3] = (__bf16)(u0.w * sc);
        t[4] = (__bf16)(u1.x * sc); t[5] = (__bf16)(u1.y * sc);
        t[6] = (__bf16)(u1.z * sc); t[7] = (__bf16)(u1.w * sc);
        wp[(q * 4 + i) ^ (r & 7)] = __builtin_bit_cast(uint4, t);
    }
}

// ---------------- pass 2: tiled GEMM (best-known: R13) ----------------
__global__ __launch_bounds__(512, 4)
void gemm(const uint4* __restrict__ ws, float* __restrict__ out)
{
    __shared__ uint4 ldsT[128 * 16];   // 32 KB  tar panel (A operand, 128 t-rows)
    __shared__ uint4 ldsX[64 * 32];    // 32 KB  f32 epilogue buffer (64 rows x 512B)

    const uint4* wsrc = ws;
    const uint4* wtar = ws + (size_t)NB * S * 16;

    const int blk = blockIdx.x;        // 0..1023 ; round-robin => b == XCD id
    const int b   = blk & 7;
    const int j   = blk >> 3;          // 0..127
    const int ts  = j >> 3;            // 0..15  source tile (128 rows)
    const int tp  = j & 7;             // 0..7   target pair (2 x 128 rows)

    const int tid  = threadIdx.x;
    const int lane = tid & 63;
    const int w    = tid >> 6;
    const int wt   = w & 1;            // 0..1  t-half (64 t-rows)
    const int wsp  = w >> 1;           // 0..3  s-quarter (32 s-rows)
    const int r16  = lane & 15;
    const int kg   = lane >> 4;        // 0..3
    const int swz  = r16 & 7;

    // ---- B operand (src rows) directly into registers, once per block ----
    bf16x8 bregs[2][4];
    #pragma unroll
    for (int n = 0; n < 2; ++n)
        #pragma unroll
        for (int ks = 0; ks < 4; ++ks) {
            const int R = b * S + ts * 128 + wsp * 32 + n * 16 + r16;
            bregs[n][ks] = __builtin_bit_cast(bf16x8, wsrc[(size_t)R * 16 + ((ks * 4 + kg) ^ swz)]);
        }

    // ---- stage first T panel ----
    const uint4* gt0 = wtar + ((size_t)(b * T + tp * 256)) * 16;
    #pragma unroll
    for (int i = 0; i < 4; ++i)
        g2l(gt0 + i * 512 + tid, &ldsT[i * 512 + w * 64]);
    asm volatile("s_waitcnt vmcnt(0)" ::: "memory");
    __builtin_amdgcn_s_barrier();
    __builtin_amdgcn_sched_barrier(0);

    f32x4 acc[4][2];

    #pragma unroll
    for (int tile = 0; tile < 2; ++tile) {
        #pragma unroll
        for (int m = 0; m < 4; ++m)
            #pragma unroll
            for (int n = 0; n < 2; ++n)
                acc[m][n] = f32x4{0.f, 0.f, 0.f, 0.f};

        #pragma unroll
        for (int ks = 0; ks < 4; ++ks) {          // K = 4 * 32
            bf16x8 at[4];
            #pragma unroll
            for (int m = 0; m < 4; ++m) {
                const int rl = wt * 64 + m * 16 + r16;
                at[m] = __builtin_bit_cast(bf16x8, ldsT[rl * 16 + ((ks * 4 + kg) ^ swz)]);
            }
            #pragma unroll
            for (int m = 0; m < 4; ++m)
                #pragma unroll
                for (int n = 0; n < 2; ++n)
                    acc[m][n] = __builtin_amdgcn_mfma_f32_16x16x32_bf16(at[m], bregs[n][ks], acc[m][n], 0, 0, 0);
        }

        if (tile == 0) {
            __syncthreads();                       // all waves done reading ldsT
            const uint4* gt1 = gt0 + 128 * 16;
            #pragma unroll
            for (int i = 0; i < 4; ++i)            // prefetch next tar panel (4 loads)
                g2l(gt1 + i * 512 + tid, &ldsT[i * 512 + w * 64]);
            __builtin_amdgcn_sched_barrier(0);     // pin: loads issued before stores
        }

        // ---- epilogue: acc -> ldsX (64-row halves) -> 2rows x 512B wave stores ----
        const int ttc = tp * 2 + tile;
        #pragma unroll
        for (int h = 0; h < 2; ++h) {
            if ((wsp >> 1) == h) {                 // waves owning s-rows [h*64, h*64+64)
                #pragma unroll
                for (int m = 0; m < 4; ++m)
                    #pragma unroll
                    for (int n = 0; n < 2; ++n) {
                        const int lrow = (wsp & 1) * 32 + n * 16 + r16;   // 0..63
                        const int col  = wt * 16 + m * 4 + kg;            // 0..31 (f32x4 slots)
                        const f32x4 a = acc[m][n];
                        f32x4 o;
                        o[0] = fmaxf(a[0], 0.f);
                        o[1] = fmaxf(a[1], 0.f);
                        o[2] = fmaxf(a[2], 0.f);
                        o[3] = fmaxf(a[3], 0.f);
                        ldsX[lrow * 32 + (col ^ (lrow & 31))] = __builtin_bit_cast(uint4, o);
                    }
            }
            asm volatile("s_waitcnt lgkmcnt(0)" ::: "memory");   // ds_writes visible
            __builtin_amdgcn_s_barrier();
            __builtin_amdgcn_sched_barrier(0);

            #pragma unroll
            for (int it = 0; it < 4; ++it) {       // 64 rows x 32 uint4 cooperative store
                const int flat = it * 512 + tid;   // 0..2047
                const int row  = flat >> 5;        // 0..63
                const int col  = flat & 31;
                const uint4 v = ldsX[row * 32 + (col ^ (row & 31))];
                float* po = out + ((size_t)(b * S + ts * 128 + h * 64 + row)) * T
                                + (size_t)ttc * 128 + col * 4;
                *(f32x4*)po = __builtin_bit_cast(f32x4, v);
            }

            // ldsX reads done before next half overwrites; stores stay in flight
            asm volatile("s_waitcnt lgkmcnt(0)" ::: "memory");
            if (tile == 0 && h == 1)
                asm volatile("s_waitcnt vmcnt(8)" ::: "memory");  // retire the 4 g2l (8 younger stores ok)
            __builtin_amdgcn_s_barrier();
            __builtin_amdgcn_sched_barrier(0);
        }
    }
}

extern "C" void kernel_launch(void* const* d_in, const int* in_sizes, int n_in,
                              void* d_out, int out_size, void* d_ws, size_t ws_size,
                              hipStream_t stream) {
    const float* src    = (const float*)d_in[0];
    const float* tar    = (const float*)d_in[1];
    const int*   mask_s = (const int*)d_in[2];
    const int*   mask_t = (const int*)d_in[3];
    float*       out    = (float*)d_out;
    uint4*       ws     = (uint4*)d_ws;

    hipLaunchKernelGGL(prep, dim3(256), dim3(512), 0, stream, src, tar, mask_s, mask_t, ws);
    hipLaunchKernelGGL(gemm, dim3(1024), dim3(512), 0, stream, ws, out);
}